// Round 6
// baseline (965.796 us; speedup 1.0000x reference)
//
#include <hip/hip_runtime.h>

#define DF 128

typedef __attribute__((ext_vector_type(8))) short bf16x8;
typedef __attribute__((ext_vector_type(4))) float f32x4;

__device__ __forceinline__ ushort f2bf(float f) {
  uint u = __float_as_uint(f);
  u += 0x7fff + ((u >> 16) & 1);
  return (ushort)(u >> 16);
}
__device__ __forceinline__ float bfl(uint v) { return __uint_as_float(v << 16); }
__device__ __forceinline__ float bfh(uint v) { return __uint_as_float(v & 0xffff0000u); }
__device__ __forceinline__ float b2f(ushort s) { return __uint_as_float(((uint)s) << 16); }

// ---------------- fused prep: castx | prepw | deg_hist(+rank) ----------------
__global__ __launch_bounds__(256) void prep_k(const float* __restrict__ x, ushort* __restrict__ xb,
                                              const float* __restrict__ W1, const float* __restrict__ W2,
                                              ushort* __restrict__ W1t, ushort* __restrict__ W2t,
                                              const int* __restrict__ dst, int e,
                                              int* __restrict__ deg, int* __restrict__ rank,
                                              int n, int B1) {
  int b = blockIdx.x, tid = threadIdx.x;
  if (b < B1) {                       // castx: n*32 float4s
    int i = b * 256 + tid;
    if (i < n * 32) {
      float4 v = reinterpret_cast<const float4*>(x)[i];
      ushort4 s; s.x = f2bf(v.x); s.y = f2bf(v.y); s.z = f2bf(v.z); s.w = f2bf(v.w);
      reinterpret_cast<ushort4*>(xb)[i] = s;
    }
  } else if (b < B1 + 256) {          // prepw
    int t = (b - B1) * 256 + tid;
    if (t < 4 * 128 * 128) {
      int i = t >> 14; int nn = (t >> 7) & 127; int kk = t & 127;
      W1t[t] = f2bf(W1[(i << 14) + kk * 128 + nn]);
    }
    if (t < 64 * 128) {
      int c64 = t >> 7; int kk = t & 127;
      int k4 = c64 >> 4; int c = c64 & 15;
      W2t[t] = f2bf(W2[k4 * 2048 + kk * 16 + c]);
    }
  } else {                            // deg hist + rank
    int i = (b - B1 - 256) * 256 + tid;
    if (i < e) rank[i] = atomicAdd(&deg[dst[i]], 1);
  }
}

// ---------------- exclusive scan (3-phase) ----------------
__global__ __launch_bounds__(256) void scan1_k(const int* __restrict__ deg, int n, int* __restrict__ partials) {
  __shared__ int sm[256];
  int base = blockIdx.x * 1024;
  int s = 0;
#pragma unroll
  for (int j = 0; j < 4; j++) { int idx = base + threadIdx.x * 4 + j; if (idx < n) s += deg[idx]; }
  sm[threadIdx.x] = s; __syncthreads();
  for (int off = 128; off > 0; off >>= 1) {
    if (threadIdx.x < off) sm[threadIdx.x] += sm[threadIdx.x + off];
    __syncthreads();
  }
  if (threadIdx.x == 0) partials[blockIdx.x] = sm[0];
}

__global__ void scan2_k(int* partials, int nb) {
  if (threadIdx.x == 0 && blockIdx.x == 0) {
    int run = 0;
    for (int i = 0; i < nb; i++) { int v = partials[i]; partials[i] = run; run += v; }
  }
}

// scan3: rowptr + dis + 256-bucket degree histogram
__global__ __launch_bounds__(256) void scan3_k(const int* __restrict__ deg, int n, int e,
                                               const int* __restrict__ partials,
                                               int* __restrict__ rowptr, float* __restrict__ dis,
                                               int* __restrict__ bhist) {
  __shared__ int sm[256];
  __shared__ int bh[256];
  int tid = threadIdx.x;
  bh[tid] = 0;
  int base = blockIdx.x * 1024;
  int loc[4]; int s = 0;
#pragma unroll
  for (int j = 0; j < 4; j++) {
    int idx = base + tid * 4 + j;
    int v = 0;
    if (idx < n) {
      v = deg[idx];
      dis[idx] = v > 0 ? rsqrtf((float)v) : 0.f;
      atomicAdd(&bh[v < 255 ? v : 255], 1);
    }
    loc[j] = s; s += v;
  }
  sm[tid] = s; __syncthreads();
  int tsum = s;
  for (int off = 1; off < 256; off <<= 1) {
    int v = (tid >= (unsigned)off) ? sm[tid - off] : 0;
    __syncthreads();
    sm[tid] += v;
    __syncthreads();
  }
  int excl = sm[tid] - tsum + partials[blockIdx.x];
#pragma unroll
  for (int j = 0; j < 4; j++) {
    int idx = base + tid * 4 + j;
    if (idx < n) rowptr[idx] = excl + loc[j];
  }
  if (blockIdx.x == 0 && tid == 0) rowptr[n] = e;
  __syncthreads();
  if (bh[tid]) atomicAdd(&bhist[tid], bh[tid]);
}

// single-block exclusive scan of 256 bucket counts -> bcursor
__global__ __launch_bounds__(256) void bscan_k(const int* __restrict__ bhist, int* __restrict__ bcursor) {
  __shared__ int sm[256];
  int tid = threadIdx.x;
  int v0 = bhist[tid];
  sm[tid] = v0; __syncthreads();
  for (int off = 1; off < 256; off <<= 1) {
    int t = (tid >= (unsigned)off) ? sm[tid - off] : 0;
    __syncthreads();
    sm[tid] += t;
    __syncthreads();
  }
  bcursor[tid] = sm[tid] - v0;
}

// ---------------- fused fill: csr scatter | degree-sorted perm place ----------------
__global__ __launch_bounds__(256) void fill_k(const int* __restrict__ src, const int* __restrict__ dst, int e,
                                              const int* __restrict__ rank, const int* __restrict__ rowptr,
                                              const float* __restrict__ dis, int2* __restrict__ ev,
                                              const int* __restrict__ deg, int* __restrict__ bcursor,
                                              int* __restrict__ perm, int n, int gE) {
  int b = blockIdx.x, tid = threadIdx.x;
  if (b < gE) {
    int i = b * 256 + tid;
    if (i < e) {
      int s = src[i], d = dst[i];
      int p = rowptr[d] + rank[i];
      float w = dis[s] * dis[d];
      int2 pk; pk.x = s; pk.y = __float_as_int(w);
      ev[p] = pk;
    }
  } else {
    int i = (b - gE) * 256 + tid;
    if (i < n) {
      int d = deg[i];
      int bk = d < 255 ? d : 255;
      int pos = atomicAdd(&bcursor[bk], 1);
      perm[pos] = i;
    }
  }
}

// ---------------- MFMA GEMM: Out(sliced) = Xb @ W (+Prev(sliced) if mode&1) ----------------
// sliced layout: slab s (16 cols) at base + s*(n*16); row node at +node*16
__global__ __launch_bounds__(256) void gemm128b_k(const ushort* __restrict__ Xb, const ushort* __restrict__ Wt,
                                                  const ushort* __restrict__ Prev,
                                                  ushort* __restrict__ Out, int n, int mode) {
  int wid = threadIdx.x >> 6, lane = threadIdx.x & 63;
  int l15 = lane & 15, kgrp = lane >> 4;
  int m = blockIdx.x * 64 + wid * 16 + l15;
  int mc = m < n ? m : n - 1;
  size_t slabsz = (size_t)n * 16;
  bf16x8 xf[4];
#pragma unroll
  for (int ks = 0; ks < 4; ks++)
    xf[ks] = *reinterpret_cast<const bf16x8*>(Xb + (size_t)mc * 128 + ks * 32 + kgrp * 8);
#pragma unroll
  for (int nt = 0; nt < 8; nt++) {
    f32x4 acc = {0.f, 0.f, 0.f, 0.f};
#pragma unroll
    for (int ks = 0; ks < 4; ks++) {
      bf16x8 wf = *reinterpret_cast<const bf16x8*>(Wt + (size_t)(nt * 16 + l15) * 128 + ks * 32 + kgrp * 8);
      acc = __builtin_amdgcn_mfma_f32_16x16x32_bf16(wf, xf[ks], acc, 0, 0, 0);
    }
    size_t soff = (size_t)nt * slabsz + (size_t)mc * 16 + kgrp * 4;
    if (mode & 1) {
      ushort4 p = *reinterpret_cast<const ushort4*>(Prev + soff);
      acc[0] += b2f(p.x); acc[1] += b2f(p.y); acc[2] += b2f(p.z); acc[3] += b2f(p.w);
    }
    if (m < n) {
      ushort4 st; st.x = f2bf(acc[0]); st.y = f2bf(acc[1]); st.z = f2bf(acc[2]); st.w = f2bf(acc[3]);
      *reinterpret_cast<ushort4*>(Out + (size_t)nt * slabsz + (size_t)m * 16 + kgrp * 4) = st;
    }
  }
}

// ---------------- Final: h1 = relu(Xb@W0 + Prev(sliced) + b1) in LDS; GB = h1 @ W2pack ----------------
__global__ __launch_bounds__(256) void gemm_last_k(const ushort* __restrict__ Xb, const ushort* __restrict__ W0t,
                                                   const ushort* __restrict__ Prev, const float* __restrict__ b1,
                                                   const ushort* __restrict__ W2t, ushort* __restrict__ GB, int n) {
  __shared__ ushort sp[4][16][136];
  int wid = threadIdx.x >> 6, lane = threadIdx.x & 63;
  int l15 = lane & 15, kgrp = lane >> 4;
  int m = blockIdx.x * 64 + wid * 16 + l15;
  int mc = m < n ? m : n - 1;
  size_t slabsz = (size_t)n * 16;
  bf16x8 xf[4];
#pragma unroll
  for (int ks = 0; ks < 4; ks++)
    xf[ks] = *reinterpret_cast<const bf16x8*>(Xb + (size_t)mc * 128 + ks * 32 + kgrp * 8);
#pragma unroll
  for (int nt = 0; nt < 8; nt++) {
    f32x4 acc = {0.f, 0.f, 0.f, 0.f};
#pragma unroll
    for (int ks = 0; ks < 4; ks++) {
      bf16x8 wf = *reinterpret_cast<const bf16x8*>(W0t + (size_t)(nt * 16 + l15) * 128 + ks * 32 + kgrp * 8);
      acc = __builtin_amdgcn_mfma_f32_16x16x32_bf16(wf, xf[ks], acc, 0, 0, 0);
    }
    int ncol = nt * 16 + kgrp * 4;
    ushort4 p = *reinterpret_cast<const ushort4*>(Prev + (size_t)nt * slabsz + (size_t)mc * 16 + kgrp * 4);
    float4 bv = *reinterpret_cast<const float4*>(b1 + ncol);
    acc[0] = fmaxf(acc[0] + b2f(p.x) + bv.x, 0.f);
    acc[1] = fmaxf(acc[1] + b2f(p.y) + bv.y, 0.f);
    acc[2] = fmaxf(acc[2] + b2f(p.z) + bv.z, 0.f);
    acc[3] = fmaxf(acc[3] + b2f(p.w) + bv.w, 0.f);
    ushort4 st; st.x = f2bf(acc[0]); st.y = f2bf(acc[1]); st.z = f2bf(acc[2]); st.w = f2bf(acc[3]);
    *reinterpret_cast<ushort4*>(&sp[wid][l15][ncol]) = st;
  }
  __syncthreads();
#pragma unroll
  for (int nt = 0; nt < 4; nt++) {
    f32x4 acc = {0.f, 0.f, 0.f, 0.f};
#pragma unroll
    for (int ks = 0; ks < 4; ks++) {
      bf16x8 af = *reinterpret_cast<const bf16x8*>(W2t + (size_t)(nt * 16 + l15) * 128 + ks * 32 + kgrp * 8);
      bf16x8 bf = *reinterpret_cast<const bf16x8*>(&sp[wid][l15][ks * 32 + kgrp * 8]);
      acc = __builtin_amdgcn_mfma_f32_16x16x32_bf16(af, bf, acc, 0, 0, 0);
    }
    if (m < n) {
      int c = nt * 16 + kgrp * 4;
      ushort4 st; st.x = f2bf(acc[0]); st.y = f2bf(acc[1]); st.z = f2bf(acc[2]); st.w = f2bf(acc[3]);
      *reinterpret_cast<ushort4*>(GB + (size_t)m * 64 + c) = st;
    }
  }
}

// ---------------- SpMM D=128, XCD-sliced slabs + degree-sorted perm ----------------
// slice = blockIdx&7 (round-robin -> one XCD per slab); 4 lanes/node x 8B; 64 nodes/block
__global__ __launch_bounds__(256) void spmm128s_k(const ushort* __restrict__ hin, ushort* __restrict__ hout,
                                                  const int* __restrict__ rowptr, const int2* __restrict__ ev,
                                                  const int* __restrict__ perm, int n) {
  int slice = blockIdx.x & 7;
  int nb = blockIdx.x >> 3;
  int g = threadIdx.x >> 2;
  int sub = threadIdx.x & 3;
  int pi = nb * 64 + g;
  if (pi >= n) return;
  int node = perm[pi];
  size_t slabsz = (size_t)n * 16;
  const ushort* slab = hin + (size_t)slice * slabsz;
  int e0 = rowptr[node], e1 = rowptr[node + 1];
  float a0 = 0.f, a1 = 0.f, a2 = 0.f, a3 = 0.f;
  for (int ee = e0; ee < e1; ee += 8) {
    int2 ed[8];
#pragma unroll
    for (int j = 0; j < 8; j++) {
      int idx = ee + j;
      int2 t = ev[idx < e1 ? idx : e0];
      if (idx >= e1) t.y = 0;
      ed[j] = t;
    }
    uint2 v[8];
#pragma unroll
    for (int j = 0; j < 8; j++)
      v[j] = *reinterpret_cast<const uint2*>(slab + (size_t)ed[j].x * 16 + sub * 4);
#pragma unroll
    for (int j = 0; j < 8; j++) {
      float w = __int_as_float(ed[j].y);
      a0 = fmaf(w, bfl(v[j].x), a0); a1 = fmaf(w, bfh(v[j].x), a1);
      a2 = fmaf(w, bfl(v[j].y), a2); a3 = fmaf(w, bfh(v[j].y), a3);
    }
  }
  uint2 st;
  st.x = (uint)f2bf(a0) | ((uint)f2bf(a1) << 16);
  st.y = (uint)f2bf(a2) | ((uint)f2bf(a3) << 16);
  *reinterpret_cast<uint2*>(hout + (size_t)slice * slabsz + (size_t)node * 16 + sub * 4) = st;
}

// ---------------- SpMM D=16 bf16 (8 threads/node, 2 cols each), perm-ordered ----------------
__global__ __launch_bounds__(256) void spmm16b_k(
    const ushort* __restrict__ in, int instride, int ioff,
    const ushort* __restrict__ add, int addstride, int aoff,
    const float* __restrict__ b2, float* __restrict__ outf, ushort* __restrict__ outb,
    const int* __restrict__ rowptr, const int2* __restrict__ ev, const int* __restrict__ perm, int n) {
  int t = blockIdx.x * 256 + threadIdx.x;
  int pi = t >> 3, cp = t & 7;
  if (pi >= n) return;
  int node = perm[pi];
  int e0 = rowptr[node], e1 = rowptr[node + 1];
  float a0 = 0.f, a1 = 0.f;
  for (int ee = e0; ee < e1; ee += 4) {
    int2 ed[4];
#pragma unroll
    for (int j = 0; j < 4; j++) {
      int idx = ee + j;
      int2 tt = ev[idx < e1 ? idx : e0];
      if (idx >= e1) tt.y = 0;
      ed[j] = tt;
    }
    uint v[4];
#pragma unroll
    for (int j = 0; j < 4; j++)
      v[j] = *reinterpret_cast<const uint*>(in + (size_t)ed[j].x * instride + ioff + cp * 2);
#pragma unroll
    for (int j = 0; j < 4; j++) {
      float wt = __int_as_float(ed[j].y);
      a0 = fmaf(wt, bfl(v[j]), a0); a1 = fmaf(wt, bfh(v[j]), a1);
    }
  }
  uint av = *reinterpret_cast<const uint*>(add + (size_t)node * addstride + aoff + cp * 2);
  a0 += bfl(av); a1 += bfh(av);
  if (outf) {
    float2 st; st.x = a0 + b2[cp * 2]; st.y = a1 + b2[cp * 2 + 1];
    *reinterpret_cast<float2*>(outf + (size_t)node * 16 + cp * 2) = st;
  } else {
    uint pk = (uint)f2bf(a0) | ((uint)f2bf(a1) << 16);
    *reinterpret_cast<uint*>(outb + (size_t)node * 16 + cp * 2) = pk;
  }
}

extern "C" void kernel_launch(void* const* d_in, const int* in_sizes, int n_in,
                              void* d_out, int out_size, void* d_ws, size_t ws_size,
                              hipStream_t stream) {
  const float* x  = (const float*)d_in[0];
  const int*   ei = (const int*)d_in[1];
  const float* W1 = (const float*)d_in[2];
  const float* b1 = (const float*)d_in[3];
  const float* W2 = (const float*)d_in[4];
  const float* b2 = (const float*)d_in[5];
  float* out = (float*)d_out;

  const int n = in_sizes[0] / DF;
  const int e = in_sizes[1] / 2;
  const int* srcp = ei;
  const int* dstp = ei + e;

  char* ws = (char*)d_ws;
  size_t off = 0;
  auto alloc = [&](size_t bytes) -> void* {
    void* p = ws + off;
    off += (bytes + 255) & ~(size_t)255;
    return p;
  };
  ushort* Xb    = (ushort*)alloc((size_t)n * DF * 2);   // x bf16; later F0/F1
  ushort* U     = (ushort*)alloc((size_t)n * DF * 2);   // sliced feature ping; later GB
  ushort* T     = (ushort*)alloc((size_t)n * DF * 2);   // sliced feature pong
  int*   misc   = (int*)alloc(((size_t)n + 512) * 4);   // deg | bhist(256) | bcursor(256)
  float* dis    = (float*)alloc((size_t)n * 4);
  int*   rowptr = (int*)alloc((size_t)(n + 1) * 4);
  int*   rank   = (int*)alloc((size_t)e * 4);
  int*   partials = (int*)alloc(1024 * 4);
  int*   perm   = (int*)alloc((size_t)n * 4);
  int2*  ev     = (int2*)alloc((size_t)e * 8);
  ushort* W1t   = (ushort*)alloc(4 * 128 * 128 * 2);
  ushort* W2t   = (ushort*)alloc(64 * 128 * 2);
  int* deg = misc;
  int* bhist = misc + n;
  int* bcursor = misc + n + 256;
  // aliases (dead buffers reused)
  ushort* GB = U;                        // n x 64 bf16
  ushort* F0 = Xb;                       // n x 16 bf16
  ushort* F1 = Xb + (size_t)n * 16;      // n x 16 bf16

  hipMemsetAsync(misc, 0, ((size_t)n + 512) * 4, stream);

  int gE = (e + 255) / 256;
  int gN = (n + 255) / 256;
  int nb = (n + 1023) / 1024;
  int B1 = (n * 32 + 255) / 256;

  prep_k<<<B1 + 256 + gE, 256, 0, stream>>>(x, Xb, W1, W2, W1t, W2t, dstp, e, deg, rank, n, B1);
  scan1_k<<<nb, 256, 0, stream>>>(deg, n, partials);
  scan2_k<<<1, 64, 0, stream>>>(partials, nb);
  scan3_k<<<nb, 256, 0, stream>>>(deg, n, e, partials, rowptr, dis, bhist);
  bscan_k<<<1, 256, 0, stream>>>(bhist, bcursor);
  fill_k<<<gE + gN, 256, 0, stream>>>(srcp, dstp, e, rank, rowptr, dis, ev, deg, bcursor, perm, n, gE);

  int gGemm = (n + 63) / 64;
  int gSpmm = ((n + 63) / 64) * 8;
  int gS16  = (n * 8 + 255) / 256;

  // ----- Layer 1 Horner: z3 -> A -> +z2 -> A -> +z1 -> A -> last(relu,+b1, GB) -----
  gemm128b_k<<<gGemm, 256, 0, stream>>>(Xb, W1t + 3 * DF * DF, nullptr, U, n, 0);
  spmm128s_k<<<gSpmm, 256, 0, stream>>>(U, T, rowptr, ev, perm, n);
  gemm128b_k<<<gGemm, 256, 0, stream>>>(Xb, W1t + 2 * DF * DF, T, U, n, 1);
  spmm128s_k<<<gSpmm, 256, 0, stream>>>(U, T, rowptr, ev, perm, n);
  gemm128b_k<<<gGemm, 256, 0, stream>>>(Xb, W1t + 1 * DF * DF, T, U, n, 1);
  spmm128s_k<<<gSpmm, 256, 0, stream>>>(U, T, rowptr, ev, perm, n);
  gemm_last_k<<<gGemm, 256, 0, stream>>>(Xb, W1t, T, b1, W2t, GB, n);

  // ----- Layer 2 Horner at D=16 (bf16 chain), perm-ordered -----
  spmm16b_k<<<gS16, 256, 0, stream>>>(GB, 64, 48, GB, 64, 32, nullptr, nullptr, F0, rowptr, ev, perm, n);
  spmm16b_k<<<gS16, 256, 0, stream>>>(F0, 16, 0,  GB, 64, 16, nullptr, nullptr, F1, rowptr, ev, perm, n);
  spmm16b_k<<<gS16, 256, 0, stream>>>(F1, 16, 0,  GB, 64, 0,  b2, out, nullptr, rowptr, ev, perm, n);
}

// Round 7
// 500.852 us; speedup vs baseline: 1.9283x; 1.9283x over previous
//
#include <hip/hip_runtime.h>

#define DF 128

typedef __attribute__((ext_vector_type(8))) short bf16x8;
typedef __attribute__((ext_vector_type(4))) float f32x4;

__device__ __forceinline__ ushort f2bf(float f) {
  uint u = __float_as_uint(f);
  u += 0x7fff + ((u >> 16) & 1);
  return (ushort)(u >> 16);
}
__device__ __forceinline__ float bfl(uint v) { return __uint_as_float(v << 16); }
__device__ __forceinline__ float bfh(uint v) { return __uint_as_float(v & 0xffff0000u); }
__device__ __forceinline__ float b2f(ushort s) { return __uint_as_float(((uint)s) << 16); }

// ---------------- fused prep: castx | prepw | sharded deg hist (+local rank) ----------------
__global__ __launch_bounds__(256) void prep_k(const float* __restrict__ x, ushort* __restrict__ xb,
                                              const float* __restrict__ W1, const float* __restrict__ W2,
                                              ushort* __restrict__ W1t, ushort* __restrict__ W2t,
                                              const int* __restrict__ dst, int e,
                                              int* __restrict__ deg_s, int* __restrict__ rank,
                                              int n, int B1) {
  int b = blockIdx.x, tid = threadIdx.x;
  if (b < B1) {                       // castx: n*32 float4s
    int i = b * 256 + tid;
    if (i < n * 32) {
      float4 v = reinterpret_cast<const float4*>(x)[i];
      ushort4 s; s.x = f2bf(v.x); s.y = f2bf(v.y); s.z = f2bf(v.z); s.w = f2bf(v.w);
      reinterpret_cast<ushort4*>(xb)[i] = s;
    }
  } else if (b < B1 + 256) {          // prepw
    int t = (b - B1) * 256 + tid;
    if (t < 4 * 128 * 128) {
      int i = t >> 14; int nn = (t >> 7) & 127; int kk = t & 127;
      W1t[t] = f2bf(W1[(i << 14) + kk * 128 + nn]);
    }
    if (t < 64 * 128) {
      int c64 = t >> 7; int kk = t & 127;
      int k4 = c64 >> 4; int c = c64 & 15;
      W2t[t] = f2bf(W2[k4 * 2048 + kk * 16 + c]);
    }
  } else {                            // sharded deg hist + local rank
    int i = (b - B1 - 256) * 256 + tid;
    if (i < e) {
      int shard = (i >> 8) & 7;
      rank[i] = atomicAdd(&deg_s[(size_t)shard * n + dst[i]], 1);
    }
  }
}

// zero the sentinel rows (row n) of gather buffers
__global__ void zero_k(ushort* Xb, ushort* Z3s, ushort* GBs3, ushort* F0, ushort* F1, int n) {
  int tid = threadIdx.x;
  if (tid < 128) { Xb[(size_t)n * 128 + tid] = 0; Z3s[(size_t)n * 128 + tid] = 0; }
  if (tid < 16) {
    GBs3[(size_t)n * 16 + tid] = 0;
    F0[(size_t)n * 16 + tid] = 0;
    F1[(size_t)n * 16 + tid] = 0;
  }
}

// fold shards: deg_total, per-shard exclusive prefix P, dis
__global__ __launch_bounds__(256) void reduce_k(const int* __restrict__ deg_s, int n,
                                                int* __restrict__ deg, int* __restrict__ P,
                                                float* __restrict__ dis) {
  int i = blockIdx.x * 256 + threadIdx.x;
  if (i >= n) return;
  int run = 0;
#pragma unroll
  for (int s = 0; s < 8; s++) {
    int v = deg_s[(size_t)s * n + i];
    P[(size_t)s * n + i] = run;
    run += v;
  }
  deg[i] = run;
  dis[i] = run > 0 ? rsqrtf((float)run) : 0.f;
}

// ---------------- exclusive scan (3-phase) ----------------
__global__ __launch_bounds__(256) void scan1_k(const int* __restrict__ deg, int n, int* __restrict__ partials) {
  __shared__ int sm[256];
  int base = blockIdx.x * 1024;
  int s = 0;
#pragma unroll
  for (int j = 0; j < 4; j++) { int idx = base + threadIdx.x * 4 + j; if (idx < n) s += deg[idx]; }
  sm[threadIdx.x] = s; __syncthreads();
  for (int off = 128; off > 0; off >>= 1) {
    if (threadIdx.x < off) sm[threadIdx.x] += sm[threadIdx.x + off];
    __syncthreads();
  }
  if (threadIdx.x == 0) partials[blockIdx.x] = sm[0];
}

__global__ void scan2_k(int* partials, int nb) {
  if (threadIdx.x == 0 && blockIdx.x == 0) {
    int run = 0;
    for (int i = 0; i < nb; i++) { int v = partials[i]; partials[i] = run; run += v; }
  }
}

__global__ __launch_bounds__(256) void scan3_k(const int* __restrict__ deg, int n, int e,
                                               const int* __restrict__ partials,
                                               int* __restrict__ rowptr) {
  __shared__ int sm[256];
  int base = blockIdx.x * 1024;
  int loc[4]; int s = 0;
#pragma unroll
  for (int j = 0; j < 4; j++) {
    int idx = base + threadIdx.x * 4 + j;
    int v = (idx < n) ? deg[idx] : 0;
    loc[j] = s; s += v;
  }
  sm[threadIdx.x] = s; __syncthreads();
  int tsum = s;
  for (int off = 1; off < 256; off <<= 1) {
    int v = (threadIdx.x >= (unsigned)off) ? sm[threadIdx.x - off] : 0;
    __syncthreads();
    sm[threadIdx.x] += v;
    __syncthreads();
  }
  int excl = sm[threadIdx.x] - tsum + partials[blockIdx.x];
#pragma unroll
  for (int j = 0; j < 4; j++) {
    int idx = base + threadIdx.x * 4 + j;
    if (idx < n) rowptr[idx] = excl + loc[j];
  }
  if (blockIdx.x == 0 && threadIdx.x == 0) rowptr[n] = e;
}

// atomic-free csr fill: col only (weights folded into feature scaling)
__global__ __launch_bounds__(256) void csr_fill_k(const int* __restrict__ src, const int* __restrict__ dst, int e,
                                                  const int* __restrict__ rank, const int* __restrict__ rowptr,
                                                  const int* __restrict__ P, int* __restrict__ colb, int n) {
  int i = blockIdx.x * 256 + threadIdx.x;
  if (i < e) {
    int d = dst[i];
    int shard = (i >> 8) & 7;
    int p = rowptr[d] + P[(size_t)shard * n + d] + rank[i];
    colb[p] = src[i];
  }
}

// ---------------- Z-GEMM: all four z_k = Xb @ W1[k] in one X pass; z3 stored scaled ----------------
#define ZGEMM_ONE(WT, OUT, SCALE)                                                             \
  {                                                                                            \
    const ushort* Wt = (WT);                                                                   \
    _Pragma("unroll")                                                                          \
    for (int nt = 0; nt < 8; nt++) {                                                           \
      f32x4 acc = {0.f, 0.f, 0.f, 0.f};                                                        \
      _Pragma("unroll")                                                                        \
      for (int ks = 0; ks < 4; ks++) {                                                         \
        bf16x8 wf = *reinterpret_cast<const bf16x8*>(Wt + (size_t)(nt * 16 + l15) * 128 + ks * 32 + kgrp * 8); \
        acc = __builtin_amdgcn_mfma_f32_16x16x32_bf16(wf, xf[ks], acc, 0, 0, 0);               \
      }                                                                                        \
      if (m < n) {                                                                             \
        int ncol = nt * 16 + kgrp * 4;                                                         \
        float sc = (SCALE) ? dm : 1.f;                                                         \
        ushort4 st; st.x = f2bf(sc * acc[0]); st.y = f2bf(sc * acc[1]);                        \
        st.z = f2bf(sc * acc[2]); st.w = f2bf(sc * acc[3]);                                    \
        *reinterpret_cast<ushort4*>((OUT) + (size_t)m * 128 + ncol) = st;                      \
      }                                                                                        \
    }                                                                                          \
  }

__global__ __launch_bounds__(256) void gemmZ_k(const ushort* __restrict__ Xb, const ushort* __restrict__ W1t,
                                               const float* __restrict__ dis,
                                               ushort* __restrict__ Z3s, ushort* __restrict__ Z2,
                                               ushort* __restrict__ Z1, ushort* __restrict__ Z0, int n) {
  int wid = threadIdx.x >> 6, lane = threadIdx.x & 63;
  int l15 = lane & 15, kgrp = lane >> 4;
  int m = blockIdx.x * 64 + wid * 16 + l15;
  int mc = m < n ? m : n - 1;
  float dm = dis[mc];
  bf16x8 xf[4];
#pragma unroll
  for (int ks = 0; ks < 4; ks++)
    xf[ks] = *reinterpret_cast<const bf16x8*>(Xb + (size_t)mc * 128 + ks * 32 + kgrp * 8);
  ZGEMM_ONE(W1t + 3 * 16384, Z3s, 1)
  ZGEMM_ONE(W1t + 2 * 16384, Z2, 0)
  ZGEMM_ONE(W1t + 1 * 16384, Z1, 0)
  ZGEMM_ONE(W1t + 0 * 16384, Z0, 0)
}

// ---------------- hop: t = dis_d * sum(hin'[src]) + zk[d]  (store scaled; last: +b1, relu, raw) ----------------
__global__ __launch_bounds__(256) void hop_k(const ushort* __restrict__ hin, const ushort* __restrict__ zk,
                                             const float* __restrict__ b1, ushort* __restrict__ hout,
                                             const int* __restrict__ rowptr, const int* __restrict__ colb,
                                             const float* __restrict__ dis, int n, int last) {
  int node = blockIdx.x * 16 + (threadIdx.x >> 4);
  int gl = threadIdx.x & 15;
  if (node >= n) return;
  int e0 = rowptr[node], e1 = rowptr[node + 1];
  float a0 = 0.f, a1 = 0.f, a2 = 0.f, a3 = 0.f, a4 = 0.f, a5 = 0.f, a6 = 0.f, a7 = 0.f;
  for (int ee = e0; ee < e1; ee += 8) {
    int c[8];
#pragma unroll
    for (int j = 0; j < 8; j++) {
      int idx = ee + j;
      c[j] = idx < e1 ? colb[idx] : n;      // row n is all-zero sentinel
    }
    uint4 v[8];
#pragma unroll
    for (int j = 0; j < 8; j++)
      v[j] = *reinterpret_cast<const uint4*>(hin + (size_t)c[j] * 128 + gl * 8);
#pragma unroll
    for (int j = 0; j < 8; j++) {
      a0 += bfl(v[j].x); a1 += bfh(v[j].x);
      a2 += bfl(v[j].y); a3 += bfh(v[j].y);
      a4 += bfl(v[j].z); a5 += bfh(v[j].z);
      a6 += bfl(v[j].w); a7 += bfh(v[j].w);
    }
  }
  float d = dis[node];
  uint4 zr = *reinterpret_cast<const uint4*>(zk + (size_t)node * 128 + gl * 8);
  float t0 = fmaf(d, a0, bfl(zr.x)), t1 = fmaf(d, a1, bfh(zr.x));
  float t2 = fmaf(d, a2, bfl(zr.y)), t3 = fmaf(d, a3, bfh(zr.y));
  float t4 = fmaf(d, a4, bfl(zr.z)), t5 = fmaf(d, a5, bfh(zr.z));
  float t6 = fmaf(d, a6, bfl(zr.w)), t7 = fmaf(d, a7, bfh(zr.w));
  uint4 st;
  if (last) {
    float4 bv0 = *reinterpret_cast<const float4*>(b1 + gl * 8);
    float4 bv1 = *reinterpret_cast<const float4*>(b1 + gl * 8 + 4);
    t0 = fmaxf(t0 + bv0.x, 0.f); t1 = fmaxf(t1 + bv0.y, 0.f);
    t2 = fmaxf(t2 + bv0.z, 0.f); t3 = fmaxf(t3 + bv0.w, 0.f);
    t4 = fmaxf(t4 + bv1.x, 0.f); t5 = fmaxf(t5 + bv1.y, 0.f);
    t6 = fmaxf(t6 + bv1.z, 0.f); t7 = fmaxf(t7 + bv1.w, 0.f);
    st.x = (uint)f2bf(t0) | ((uint)f2bf(t1) << 16);
    st.y = (uint)f2bf(t2) | ((uint)f2bf(t3) << 16);
    st.z = (uint)f2bf(t4) | ((uint)f2bf(t5) << 16);
    st.w = (uint)f2bf(t6) | ((uint)f2bf(t7) << 16);
  } else {
    st.x = (uint)f2bf(d * t0) | ((uint)f2bf(d * t1) << 16);
    st.y = (uint)f2bf(d * t2) | ((uint)f2bf(d * t3) << 16);
    st.z = (uint)f2bf(d * t4) | ((uint)f2bf(d * t5) << 16);
    st.w = (uint)f2bf(d * t6) | ((uint)f2bf(d * t7) << 16);
  }
  *reinterpret_cast<uint4*>(hout + (size_t)node * 128 + gl * 8) = st;
}

// ---------------- final GEMM: GB = h1 @ W2pack (raw) + GBs3 = dis * g3 ----------------
__global__ __launch_bounds__(256) void gemm_last_k(const ushort* __restrict__ h1, const ushort* __restrict__ W2t,
                                                   const float* __restrict__ dis,
                                                   ushort* __restrict__ GB, ushort* __restrict__ GBs3, int n) {
  int wid = threadIdx.x >> 6, lane = threadIdx.x & 63;
  int l15 = lane & 15, kgrp = lane >> 4;
  int m = blockIdx.x * 64 + wid * 16 + l15;
  int mc = m < n ? m : n - 1;
  float dm = dis[mc];
  bf16x8 xf[4];
#pragma unroll
  for (int ks = 0; ks < 4; ks++)
    xf[ks] = *reinterpret_cast<const bf16x8*>(h1 + (size_t)mc * 128 + ks * 32 + kgrp * 8);
#pragma unroll
  for (int nt = 0; nt < 4; nt++) {
    f32x4 acc = {0.f, 0.f, 0.f, 0.f};
#pragma unroll
    for (int ks = 0; ks < 4; ks++) {
      bf16x8 wf = *reinterpret_cast<const bf16x8*>(W2t + (size_t)(nt * 16 + l15) * 128 + ks * 32 + kgrp * 8);
      acc = __builtin_amdgcn_mfma_f32_16x16x32_bf16(wf, xf[ks], acc, 0, 0, 0);
    }
    if (m < n) {
      int ncol = nt * 16 + kgrp * 4;
      ushort4 st; st.x = f2bf(acc[0]); st.y = f2bf(acc[1]); st.z = f2bf(acc[2]); st.w = f2bf(acc[3]);
      *reinterpret_cast<ushort4*>(GB + (size_t)m * 64 + ncol) = st;
      if (nt == 3) {
        ushort4 ss; ss.x = f2bf(dm * acc[0]); ss.y = f2bf(dm * acc[1]);
        ss.z = f2bf(dm * acc[2]); ss.w = f2bf(dm * acc[3]);
        *reinterpret_cast<ushort4*>(GBs3 + (size_t)m * 16 + kgrp * 4) = ss;
      }
    }
  }
}

// ---------------- SpMM D=16: t = dis_d * sum(in'[src]) + add[d]  (scaled store or final f32) ----------------
__global__ __launch_bounds__(256) void spmm16_k(const ushort* __restrict__ in,
                                                const ushort* __restrict__ addraw, int addstride,
                                                const float* __restrict__ b2,
                                                float* __restrict__ outf, ushort* __restrict__ outb,
                                                const int* __restrict__ rowptr, const int* __restrict__ colb,
                                                const float* __restrict__ dis, int n) {
  int t = blockIdx.x * 256 + threadIdx.x;
  int node = t >> 3, cp = t & 7;
  if (node >= n) return;
  int e0 = rowptr[node], e1 = rowptr[node + 1];
  float a0 = 0.f, a1 = 0.f;
  for (int ee = e0; ee < e1; ee += 4) {
    int c[4];
#pragma unroll
    for (int j = 0; j < 4; j++) {
      int idx = ee + j;
      c[j] = idx < e1 ? colb[idx] : n;
    }
    uint v[4];
#pragma unroll
    for (int j = 0; j < 4; j++)
      v[j] = *reinterpret_cast<const uint*>(in + (size_t)c[j] * 16 + cp * 2);
#pragma unroll
    for (int j = 0; j < 4; j++) { a0 += bfl(v[j]); a1 += bfh(v[j]); }
  }
  float d = dis[node];
  uint av = *reinterpret_cast<const uint*>(addraw + (size_t)node * addstride + cp * 2);
  float t0 = fmaf(d, a0, b2f((ushort)(av & 0xffff)));
  float t1 = fmaf(d, a1, b2f((ushort)(av >> 16)));
  if (outf) {
    float2 st; st.x = t0 + b2[cp * 2]; st.y = t1 + b2[cp * 2 + 1];
    *reinterpret_cast<float2*>(outf + (size_t)node * 16 + cp * 2) = st;
  } else {
    uint pk = (uint)f2bf(d * t0) | ((uint)f2bf(d * t1) << 16);
    *reinterpret_cast<uint*>(outb + (size_t)node * 16 + cp * 2) = pk;
  }
}

extern "C" void kernel_launch(void* const* d_in, const int* in_sizes, int n_in,
                              void* d_out, int out_size, void* d_ws, size_t ws_size,
                              hipStream_t stream) {
  const float* x  = (const float*)d_in[0];
  const int*   ei = (const int*)d_in[1];
  const float* W1 = (const float*)d_in[2];
  const float* b1 = (const float*)d_in[3];
  const float* W2 = (const float*)d_in[4];
  const float* b2 = (const float*)d_in[5];
  float* out = (float*)d_out;

  const int n = in_sizes[0] / DF;
  const int e = in_sizes[1] / 2;
  const int* srcp = ei;
  const int* dstp = ei + e;

  char* ws = (char*)d_ws;
  size_t off = 0;
  auto alloc = [&](size_t bytes) -> void* {
    void* p = ws + off;
    off += (bytes + 255) & ~(size_t)255;
    return p;
  };
  ushort* Xb   = (ushort*)alloc((size_t)(n + 1) * 128 * 2);  // x' bf16; later T' (hop1 out), then h1
  ushort* Z3s  = (ushort*)alloc((size_t)(n + 1) * 128 * 2);  // dis*z3; later U' (hop2 out)
  ushort* Z2   = (ushort*)alloc((size_t)n * 128 * 2);
  ushort* Z1   = (ushort*)alloc((size_t)n * 128 * 2);
  ushort* Z0   = (ushort*)alloc((size_t)n * 128 * 2);        // later GB (n x 64)
  int*   deg_s = (int*)alloc((size_t)8 * n * 4);             // sharded hist
  int*   P     = (int*)alloc((size_t)8 * n * 4);             // per-shard prefix
  int*   deg   = (int*)alloc((size_t)n * 4);
  float* dis   = (float*)alloc((size_t)n * 4);
  int*   rowptr= (int*)alloc((size_t)(n + 1) * 4);
  int*   rank  = (int*)alloc((size_t)e * 4);
  int*   partials = (int*)alloc(1024 * 4);
  int*   colb  = (int*)alloc((size_t)e * 4);
  ushort* W1t  = (ushort*)alloc(4 * 128 * 128 * 2);
  ushort* W2t  = (ushort*)alloc(64 * 128 * 2);
  ushort* GBs3 = (ushort*)alloc((size_t)(n + 1) * 16 * 2);
  ushort* F0   = (ushort*)alloc((size_t)(n + 1) * 16 * 2);
  ushort* F1   = (ushort*)alloc((size_t)(n + 1) * 16 * 2);
  // aliases
  ushort* Tp = Xb;    // hop1 output (scaled), gathered by hop2  (Xb dead after gemmZ)
  ushort* Up = Z3s;   // hop2 output (scaled), gathered by hop3  (Z3s dead after hop1)
  ushort* h1 = Xb;    // hop3 output (raw)                        (Tp dead after hop2)
  ushort* GB = Z0;    // gemm_last output (raw n x 64)            (Z0 dead after hop3)

  hipMemsetAsync(deg_s, 0, (size_t)8 * n * 4, stream);

  int gE = (e + 255) / 256;
  int gN = (n + 255) / 256;
  int nb = (n + 1023) / 1024;
  int B1 = (n * 32 + 255) / 256;

  zero_k<<<1, 128, 0, stream>>>(Xb, Z3s, GBs3, F0, F1, n);
  prep_k<<<B1 + 256 + gE, 256, 0, stream>>>(x, Xb, W1, W2, W1t, W2t, dstp, e, deg_s, rank, n, B1);
  reduce_k<<<gN, 256, 0, stream>>>(deg_s, n, deg, P, dis);
  scan1_k<<<nb, 256, 0, stream>>>(deg, n, partials);
  scan2_k<<<1, 64, 0, stream>>>(partials, nb);
  scan3_k<<<nb, 256, 0, stream>>>(deg, n, e, partials, rowptr);
  csr_fill_k<<<gE, 256, 0, stream>>>(srcp, dstp, e, rank, rowptr, P, colb, n);

  int gGemm = (n + 63) / 64;
  int gHop  = (n + 15) / 16;
  int gS16  = (n * 8 + 255) / 256;

  // ----- Layer 1 Horner (pre-scaled gathers): p3=z3; p2=A p3+z2; p1=A p2+z1; h1=relu(A p1+z0+b1)
  gemmZ_k<<<gGemm, 256, 0, stream>>>(Xb, W1t, dis, Z3s, Z2, Z1, Z0, n);
  hop_k<<<gHop, 256, 0, stream>>>(Z3s, Z2, nullptr, Tp, rowptr, colb, dis, n, 0);
  hop_k<<<gHop, 256, 0, stream>>>(Tp, Z1, nullptr, Up, rowptr, colb, dis, n, 0);
  hop_k<<<gHop, 256, 0, stream>>>(Up, Z0, b1, h1, rowptr, colb, dis, n, 1);
  gemm_last_k<<<gGemm, 256, 0, stream>>>(h1, W2t, dis, GB, GBs3, n);

  // ----- Layer 2 Horner at D=16: f2=A g3'+g2; f1=A f2'+g1; out=A f1'+g0+b2
  spmm16_k<<<gS16, 256, 0, stream>>>(GBs3, GB + 32, 64, nullptr, nullptr, F0, rowptr, colb, dis, n);
  spmm16_k<<<gS16, 256, 0, stream>>>(F0,   GB + 16, 64, nullptr, nullptr, F1, rowptr, colb, dis, n);
  spmm16_k<<<gS16, 256, 0, stream>>>(F1,   GB + 0,  64, b2, out, nullptr, rowptr, colb, dis, n);
}

// Round 8
// 431.457 us; speedup vs baseline: 2.2385x; 1.1608x over previous
//
#include <hip/hip_runtime.h>

#define DF 128

typedef __attribute__((ext_vector_type(8))) short bf16x8;
typedef __attribute__((ext_vector_type(4))) float f32x4;

__device__ __forceinline__ ushort f2bf(float f) {
  uint u = __float_as_uint(f);
  u += 0x7fff + ((u >> 16) & 1);
  return (ushort)(u >> 16);
}
__device__ __forceinline__ float bfl(uint v) { return __uint_as_float(v << 16); }
__device__ __forceinline__ float bfh(uint v) { return __uint_as_float(v & 0xffff0000u); }
__device__ __forceinline__ float b2f(ushort s) { return __uint_as_float(((uint)s) << 16); }

__device__ __forceinline__ void gload16(const ushort* g, ushort* l) {
  __builtin_amdgcn_global_load_lds((const __attribute__((address_space(1))) void*)g,
                                   (__attribute__((address_space(3))) void*)l, 16, 0, 0);
}

// ---------------- fused prep: castx | prepw (fragment-linear) | sharded deg hist ----------------
// W1f[o]: o = ((k*32 + nt*4 + ks)*64 + lane)*8 + j  -> W1[k][kk][nn], nn=nt*16+(lane&15), kk=ks*32+(lane>>4)*8+j
// W2f[o]: o = ((nt*4 + ks)*64 + lane)*8 + j         -> W2[nt][kk][lane&15]
__global__ __launch_bounds__(256) void prep_k(const float* __restrict__ x, ushort* __restrict__ xb,
                                              const float* __restrict__ W1, const float* __restrict__ W2,
                                              ushort* __restrict__ W1f, ushort* __restrict__ W2f,
                                              const int* __restrict__ dst, int e,
                                              int* __restrict__ deg_s, int* __restrict__ rank,
                                              int n, int B1) {
  int b = blockIdx.x, tid = threadIdx.x;
  if (b < B1) {                       // castx: n*32 float4s
    int i = b * 256 + tid;
    if (i < n * 32) {
      float4 v = reinterpret_cast<const float4*>(x)[i];
      ushort4 s; s.x = f2bf(v.x); s.y = f2bf(v.y); s.z = f2bf(v.z); s.w = f2bf(v.w);
      reinterpret_cast<ushort4*>(xb)[i] = s;
    }
  } else if (b < B1 + 256) {          // prepw
    int t = (b - B1) * 256 + tid;
    {
      int k = t >> 14, rem = t & 16383;
      int frag = rem >> 3, j = rem & 7;
      int nt = frag >> 8, ks = (frag >> 6) & 3, lane = frag & 63;
      int nn = nt * 16 + (lane & 15);
      int kk = ks * 32 + (lane >> 4) * 8 + j;
      W1f[t] = f2bf(W1[k * 16384 + kk * 128 + nn]);
    }
    if (t < 8192) {
      int frag = t >> 3, j = t & 7;
      int nt = frag >> 8, ks = (frag >> 6) & 3, lane = frag & 63;
      int kk = ks * 32 + (lane >> 4) * 8 + j;
      W2f[t] = f2bf(W2[nt * 2048 + kk * 16 + (lane & 15)]);
    }
  } else {                            // sharded deg hist + local rank
    int i = (b - B1 - 256) * 256 + tid;
    if (i < e) {
      int shard = (i >> 8) & 7;
      rank[i] = atomicAdd(&deg_s[(size_t)shard * n + dst[i]], 1);
    }
  }
}

// zero the sentinel rows (row n) of gather buffers
__global__ void zero_k(ushort* Xb, ushort* Z3s, ushort* GBs3, ushort* F0, ushort* F1, int n) {
  int tid = threadIdx.x;
  if (tid < 128) { Xb[(size_t)n * 128 + tid] = 0; Z3s[(size_t)n * 128 + tid] = 0; }
  if (tid < 16) {
    GBs3[(size_t)n * 16 + tid] = 0;
    F0[(size_t)n * 16 + tid] = 0;
    F1[(size_t)n * 16 + tid] = 0;
  }
}

// fold shards: deg_total, per-shard exclusive prefix P, dis
__global__ __launch_bounds__(256) void reduce_k(const int* __restrict__ deg_s, int n,
                                                int* __restrict__ deg, int* __restrict__ P,
                                                float* __restrict__ dis) {
  int i = blockIdx.x * 256 + threadIdx.x;
  if (i >= n) return;
  int run = 0;
#pragma unroll
  for (int s = 0; s < 8; s++) {
    int v = deg_s[(size_t)s * n + i];
    P[(size_t)s * n + i] = run;
    run += v;
  }
  deg[i] = run;
  dis[i] = run > 0 ? rsqrtf((float)run) : 0.f;
}

// ---------------- exclusive scan (3-phase) ----------------
__global__ __launch_bounds__(256) void scan1_k(const int* __restrict__ deg, int n, int* __restrict__ partials) {
  __shared__ int sm[256];
  int base = blockIdx.x * 1024;
  int s = 0;
#pragma unroll
  for (int j = 0; j < 4; j++) { int idx = base + threadIdx.x * 4 + j; if (idx < n) s += deg[idx]; }
  sm[threadIdx.x] = s; __syncthreads();
  for (int off = 128; off > 0; off >>= 1) {
    if (threadIdx.x < off) sm[threadIdx.x] += sm[threadIdx.x + off];
    __syncthreads();
  }
  if (threadIdx.x == 0) partials[blockIdx.x] = sm[0];
}

__global__ void scan2_k(int* partials, int nb) {
  if (threadIdx.x == 0 && blockIdx.x == 0) {
    int run = 0;
    for (int i = 0; i < nb; i++) { int v = partials[i]; partials[i] = run; run += v; }
  }
}

__global__ __launch_bounds__(256) void scan3_k(const int* __restrict__ deg, int n, int e,
                                               const int* __restrict__ partials,
                                               int* __restrict__ rowptr) {
  __shared__ int sm[256];
  int base = blockIdx.x * 1024;
  int loc[4]; int s = 0;
#pragma unroll
  for (int j = 0; j < 4; j++) {
    int idx = base + threadIdx.x * 4 + j;
    int v = (idx < n) ? deg[idx] : 0;
    loc[j] = s; s += v;
  }
  sm[threadIdx.x] = s; __syncthreads();
  int tsum = s;
  for (int off = 1; off < 256; off <<= 1) {
    int v = (threadIdx.x >= (unsigned)off) ? sm[threadIdx.x - off] : 0;
    __syncthreads();
    sm[threadIdx.x] += v;
    __syncthreads();
  }
  int excl = sm[threadIdx.x] - tsum + partials[blockIdx.x];
#pragma unroll
  for (int j = 0; j < 4; j++) {
    int idx = base + threadIdx.x * 4 + j;
    if (idx < n) rowptr[idx] = excl + loc[j];
  }
  if (blockIdx.x == 0 && threadIdx.x == 0) rowptr[n] = e;
}

// atomic-free csr fill: col only
__global__ __launch_bounds__(256) void csr_fill_k(const int* __restrict__ src, const int* __restrict__ dst, int e,
                                                  const int* __restrict__ rank, const int* __restrict__ rowptr,
                                                  const int* __restrict__ P, int* __restrict__ colb, int n) {
  int i = blockIdx.x * 256 + threadIdx.x;
  if (i < e) {
    int d = dst[i];
    int shard = (i >> 8) & 7;
    int p = rowptr[d] + P[(size_t)shard * n + d] + rank[i];
    colb[p] = src[i];
  }
}

// ---------------- Z-GEMM: LDS-staged W (double-buffer), 128 rows/block, 2 row-frags/wave ----------------
__global__ __launch_bounds__(256) void gemmZ_k(const ushort* __restrict__ Xb, const ushort* __restrict__ W1f,
                                               const float* __restrict__ dis,
                                               ushort* __restrict__ Z3s, ushort* __restrict__ Z2,
                                               ushort* __restrict__ Z1, ushort* __restrict__ Z0, int n) {
  __shared__ ushort wbuf[2][16384];   // 2 x 32 KB
  int tid = threadIdx.x;
  int wid = tid >> 6, lane = tid & 63;
  int l15 = lane & 15, kgrp = lane >> 4;
  int m0 = blockIdx.x * 128 + wid * 32 + l15;
  int m1 = m0 + 16;
  int mc0 = m0 < n ? m0 : n - 1;
  int mc1 = m1 < n ? m1 : n - 1;
  float d0 = dis[mc0], d1 = dis[mc1];
  bf16x8 xf0[4], xf1[4];
#pragma unroll
  for (int ks = 0; ks < 4; ks++) {
    xf0[ks] = *reinterpret_cast<const bf16x8*>(Xb + (size_t)mc0 * 128 + ks * 32 + kgrp * 8);
    xf1[ks] = *reinterpret_cast<const bf16x8*>(Xb + (size_t)mc1 * 128 + ks * 32 + kgrp * 8);
  }

#define STAGE(B, K)                                                              \
  {                                                                              \
    const ushort* gsrc = W1f + (size_t)(K) * 16384;                              \
    _Pragma("unroll")                                                            \
    for (int it = 0; it < 8; it++) {                                             \
      int off = (it * 256 + wid * 64) * 8;                                       \
      gload16(gsrc + off + lane * 8, &wbuf[B][off + lane * 8]);                  \
    }                                                                            \
  }

  STAGE(0, 3)
  __syncthreads();

#pragma unroll
  for (int kk = 0; kk < 4; kk++) {
    const int k = 3 - kk;
    const int cb = kk & 1;
    if (kk < 3) STAGE(cb ^ 1, k - 1)
    f32x4 acc0[8], acc1[8];
#pragma unroll
    for (int nt = 0; nt < 8; nt++) {
      acc0[nt] = {0.f, 0.f, 0.f, 0.f};
      acc1[nt] = {0.f, 0.f, 0.f, 0.f};
    }
#pragma unroll
    for (int ks = 0; ks < 4; ks++) {
#pragma unroll
      for (int nt = 0; nt < 8; nt++) {
        bf16x8 wf = *reinterpret_cast<const bf16x8*>(&wbuf[cb][((nt * 4 + ks) * 64 + lane) * 8]);
        acc0[nt] = __builtin_amdgcn_mfma_f32_16x16x32_bf16(wf, xf0[ks], acc0[nt], 0, 0, 0);
        acc1[nt] = __builtin_amdgcn_mfma_f32_16x16x32_bf16(wf, xf1[ks], acc1[nt], 0, 0, 0);
      }
    }
    ushort* Out = (k == 3) ? Z3s : (k == 2) ? Z2 : (k == 1) ? Z1 : Z0;
    float sc0 = (k == 3) ? d0 : 1.f;
    float sc1 = (k == 3) ? d1 : 1.f;
#pragma unroll
    for (int nt = 0; nt < 8; nt++) {
      int ncol = nt * 16 + kgrp * 4;
      if (m0 < n) {
        ushort4 st; st.x = f2bf(sc0 * acc0[nt][0]); st.y = f2bf(sc0 * acc0[nt][1]);
        st.z = f2bf(sc0 * acc0[nt][2]); st.w = f2bf(sc0 * acc0[nt][3]);
        *reinterpret_cast<ushort4*>(Out + (size_t)m0 * 128 + ncol) = st;
      }
      if (m1 < n) {
        ushort4 st; st.x = f2bf(sc1 * acc1[nt][0]); st.y = f2bf(sc1 * acc1[nt][1]);
        st.z = f2bf(sc1 * acc1[nt][2]); st.w = f2bf(sc1 * acc1[nt][3]);
        *reinterpret_cast<ushort4*>(Out + (size_t)m1 * 128 + ncol) = st;
      }
    }
    __syncthreads();
  }
#undef STAGE
}

// ---------------- hop: t = dis_d * sum(hin'[src]) + zk[d] ----------------
__global__ __launch_bounds__(256) void hop_k(const ushort* __restrict__ hin, const ushort* __restrict__ zk,
                                             const float* __restrict__ b1, ushort* __restrict__ hout,
                                             const int* __restrict__ rowptr, const int* __restrict__ colb,
                                             const float* __restrict__ dis, int n, int last) {
  int node = blockIdx.x * 16 + (threadIdx.x >> 4);
  int gl = threadIdx.x & 15;
  if (node >= n) return;
  int e0 = rowptr[node], e1 = rowptr[node + 1];
  float a0 = 0.f, a1 = 0.f, a2 = 0.f, a3 = 0.f, a4 = 0.f, a5 = 0.f, a6 = 0.f, a7 = 0.f;
  for (int ee = e0; ee < e1; ee += 8) {
    int c[8];
#pragma unroll
    for (int j = 0; j < 8; j++) {
      int idx = ee + j;
      c[j] = idx < e1 ? colb[idx] : n;      // row n is all-zero sentinel
    }
    uint4 v[8];
#pragma unroll
    for (int j = 0; j < 8; j++)
      v[j] = *reinterpret_cast<const uint4*>(hin + (size_t)c[j] * 128 + gl * 8);
#pragma unroll
    for (int j = 0; j < 8; j++) {
      a0 += bfl(v[j].x); a1 += bfh(v[j].x);
      a2 += bfl(v[j].y); a3 += bfh(v[j].y);
      a4 += bfl(v[j].z); a5 += bfh(v[j].z);
      a6 += bfl(v[j].w); a7 += bfh(v[j].w);
    }
  }
  float d = dis[node];
  uint4 zr = *reinterpret_cast<const uint4*>(zk + (size_t)node * 128 + gl * 8);
  float t0 = fmaf(d, a0, bfl(zr.x)), t1 = fmaf(d, a1, bfh(zr.x));
  float t2 = fmaf(d, a2, bfl(zr.y)), t3 = fmaf(d, a3, bfh(zr.y));
  float t4 = fmaf(d, a4, bfl(zr.z)), t5 = fmaf(d, a5, bfh(zr.z));
  float t6 = fmaf(d, a6, bfl(zr.w)), t7 = fmaf(d, a7, bfh(zr.w));
  uint4 st;
  if (last) {
    float4 bv0 = *reinterpret_cast<const float4*>(b1 + gl * 8);
    float4 bv1 = *reinterpret_cast<const float4*>(b1 + gl * 8 + 4);
    t0 = fmaxf(t0 + bv0.x, 0.f); t1 = fmaxf(t1 + bv0.y, 0.f);
    t2 = fmaxf(t2 + bv0.z, 0.f); t3 = fmaxf(t3 + bv0.w, 0.f);
    t4 = fmaxf(t4 + bv1.x, 0.f); t5 = fmaxf(t5 + bv1.y, 0.f);
    t6 = fmaxf(t6 + bv1.z, 0.f); t7 = fmaxf(t7 + bv1.w, 0.f);
    st.x = (uint)f2bf(t0) | ((uint)f2bf(t1) << 16);
    st.y = (uint)f2bf(t2) | ((uint)f2bf(t3) << 16);
    st.z = (uint)f2bf(t4) | ((uint)f2bf(t5) << 16);
    st.w = (uint)f2bf(t6) | ((uint)f2bf(t7) << 16);
  } else {
    st.x = (uint)f2bf(d * t0) | ((uint)f2bf(d * t1) << 16);
    st.y = (uint)f2bf(d * t2) | ((uint)f2bf(d * t3) << 16);
    st.z = (uint)f2bf(d * t4) | ((uint)f2bf(d * t5) << 16);
    st.w = (uint)f2bf(d * t6) | ((uint)f2bf(d * t7) << 16);
  }
  *reinterpret_cast<uint4*>(hout + (size_t)node * 128 + gl * 8) = st;
}

// ---------------- final GEMM: GB = h1 @ W2pack (raw) + GBs3 = dis * g3 ----------------
__global__ __launch_bounds__(256) void gemm_last_k(const ushort* __restrict__ h1, const ushort* __restrict__ W2f,
                                                   const float* __restrict__ dis,
                                                   ushort* __restrict__ GB, ushort* __restrict__ GBs3, int n) {
  int wid = threadIdx.x >> 6, lane = threadIdx.x & 63;
  int kgrp = lane >> 4;
  int m = blockIdx.x * 64 + wid * 16 + (lane & 15);
  int mc = m < n ? m : n - 1;
  float dm = dis[mc];
  bf16x8 xf[4];
#pragma unroll
  for (int ks = 0; ks < 4; ks++)
    xf[ks] = *reinterpret_cast<const bf16x8*>(h1 + (size_t)mc * 128 + ks * 32 + kgrp * 8);
#pragma unroll
  for (int nt = 0; nt < 4; nt++) {
    f32x4 acc = {0.f, 0.f, 0.f, 0.f};
#pragma unroll
    for (int ks = 0; ks < 4; ks++) {
      bf16x8 wf = *reinterpret_cast<const bf16x8*>(W2f + (size_t)((nt * 4 + ks) * 64 + lane) * 8);
      acc = __builtin_amdgcn_mfma_f32_16x16x32_bf16(wf, xf[ks], acc, 0, 0, 0);
    }
    if (m < n) {
      int ncol = nt * 16 + kgrp * 4;
      ushort4 st; st.x = f2bf(acc[0]); st.y = f2bf(acc[1]); st.z = f2bf(acc[2]); st.w = f2bf(acc[3]);
      *reinterpret_cast<ushort4*>(GB + (size_t)m * 64 + ncol) = st;
      if (nt == 3) {
        ushort4 ss; ss.x = f2bf(dm * acc[0]); ss.y = f2bf(dm * acc[1]);
        ss.z = f2bf(dm * acc[2]); ss.w = f2bf(dm * acc[3]);
        *reinterpret_cast<ushort4*>(GBs3 + (size_t)m * 16 + kgrp * 4) = ss;
      }
    }
  }
}

// ---------------- SpMM D=16: t = dis_d * sum(in'[src]) + add[d] ----------------
__global__ __launch_bounds__(256) void spmm16_k(const ushort* __restrict__ in,
                                                const ushort* __restrict__ addraw, int addstride,
                                                const float* __restrict__ b2,
                                                float* __restrict__ outf, ushort* __restrict__ outb,
                                                const int* __restrict__ rowptr, const int* __restrict__ colb,
                                                const float* __restrict__ dis, int n) {
  int t = blockIdx.x * 256 + threadIdx.x;
  int node = t >> 3, cp = t & 7;
  if (node >= n) return;
  int e0 = rowptr[node], e1 = rowptr[node + 1];
  float a0 = 0.f, a1 = 0.f;
  for (int ee = e0; ee < e1; ee += 4) {
    int c[4];
#pragma unroll
    for (int j = 0; j < 4; j++) {
      int idx = ee + j;
      c[j] = idx < e1 ? colb[idx] : n;
    }
    uint v[4];
#pragma unroll
    for (int j = 0; j < 4; j++)
      v[j] = *reinterpret_cast<const uint*>(in + (size_t)c[j] * 16 + cp * 2);
#pragma unroll
    for (int j = 0; j < 4; j++) { a0 += bfl(v[j]); a1 += bfh(v[j]); }
  }
  float d = dis[node];
  uint av = *reinterpret_cast<const uint*>(addraw + (size_t)node * addstride + cp * 2);
  float t0 = fmaf(d, a0, b2f((ushort)(av & 0xffff)));
  float t1 = fmaf(d, a1, b2f((ushort)(av >> 16)));
  if (outf) {
    float2 st; st.x = t0 + b2[cp * 2]; st.y = t1 + b2[cp * 2 + 1];
    *reinterpret_cast<float2*>(outf + (size_t)node * 16 + cp * 2) = st;
  } else {
    uint pk = (uint)f2bf(d * t0) | ((uint)f2bf(d * t1) << 16);
    *reinterpret_cast<uint*>(outb + (size_t)node * 16 + cp * 2) = pk;
  }
}

extern "C" void kernel_launch(void* const* d_in, const int* in_sizes, int n_in,
                              void* d_out, int out_size, void* d_ws, size_t ws_size,
                              hipStream_t stream) {
  const float* x  = (const float*)d_in[0];
  const int*   ei = (const int*)d_in[1];
  const float* W1 = (const float*)d_in[2];
  const float* b1 = (const float*)d_in[3];
  const float* W2 = (const float*)d_in[4];
  const float* b2 = (const float*)d_in[5];
  float* out = (float*)d_out;

  const int n = in_sizes[0] / DF;
  const int e = in_sizes[1] / 2;
  const int* srcp = ei;
  const int* dstp = ei + e;

  char* ws = (char*)d_ws;
  size_t off = 0;
  auto alloc = [&](size_t bytes) -> void* {
    void* p = ws + off;
    off += (bytes + 255) & ~(size_t)255;
    return p;
  };
  ushort* Xb   = (ushort*)alloc((size_t)(n + 1) * 128 * 2);  // x' bf16; later T' (hop1 out), then h1
  ushort* Z3s  = (ushort*)alloc((size_t)(n + 1) * 128 * 2);  // dis*z3; later U' (hop2 out)
  ushort* Z2   = (ushort*)alloc((size_t)n * 128 * 2);
  ushort* Z1   = (ushort*)alloc((size_t)n * 128 * 2);
  ushort* Z0   = (ushort*)alloc((size_t)n * 128 * 2);        // later GB (n x 64)
  int*   deg_s = (int*)alloc((size_t)8 * n * 4);             // sharded hist
  int*   P     = (int*)alloc((size_t)8 * n * 4);             // per-shard prefix
  int*   deg   = (int*)alloc((size_t)n * 4);
  float* dis   = (float*)alloc((size_t)n * 4);
  int*   rowptr= (int*)alloc((size_t)(n + 1) * 4);
  int*   rank  = (int*)alloc((size_t)e * 4);
  int*   partials = (int*)alloc(1024 * 4);
  int*   colb  = (int*)alloc((size_t)e * 4);
  ushort* W1f  = (ushort*)alloc(4 * 128 * 128 * 2);
  ushort* W2f  = (ushort*)alloc(64 * 128 * 2);
  ushort* GBs3 = (ushort*)alloc((size_t)(n + 1) * 16 * 2);
  ushort* F0   = (ushort*)alloc((size_t)(n + 1) * 16 * 2);
  ushort* F1   = (ushort*)alloc((size_t)(n + 1) * 16 * 2);
  // aliases
  ushort* Tp = Xb;    // hop1 output (scaled)
  ushort* Up = Z3s;   // hop2 output (scaled)
  ushort* h1 = Xb;    // hop3 output (raw)
  ushort* GB = Z0;    // gemm_last output (raw n x 64)

  hipMemsetAsync(deg_s, 0, (size_t)8 * n * 4, stream);

  int gE = (e + 255) / 256;
  int gN = (n + 255) / 256;
  int nb = (n + 1023) / 1024;
  int B1 = (n * 32 + 255) / 256;

  zero_k<<<1, 128, 0, stream>>>(Xb, Z3s, GBs3, F0, F1, n);
  prep_k<<<B1 + 256 + gE, 256, 0, stream>>>(x, Xb, W1, W2, W1f, W2f, dstp, e, deg_s, rank, n, B1);
  reduce_k<<<gN, 256, 0, stream>>>(deg_s, n, deg, P, dis);
  scan1_k<<<nb, 256, 0, stream>>>(deg, n, partials);
  scan2_k<<<1, 64, 0, stream>>>(partials, nb);
  scan3_k<<<nb, 256, 0, stream>>>(deg, n, e, partials, rowptr);
  csr_fill_k<<<gE, 256, 0, stream>>>(srcp, dstp, e, rank, rowptr, P, colb, n);

  int gGemmZ = (n + 127) / 128;
  int gGemm = (n + 63) / 64;
  int gHop  = (n + 15) / 16;
  int gS16  = (n * 8 + 255) / 256;

  // ----- Layer 1 Horner (pre-scaled gathers): p3=z3; p2=A p3+z2; p1=A p2+z1; h1=relu(A p1+z0+b1)
  gemmZ_k<<<gGemmZ, 256, 0, stream>>>(Xb, W1f, dis, Z3s, Z2, Z1, Z0, n);
  hop_k<<<gHop, 256, 0, stream>>>(Z3s, Z2, nullptr, Tp, rowptr, colb, dis, n, 0);
  hop_k<<<gHop, 256, 0, stream>>>(Tp, Z1, nullptr, Up, rowptr, colb, dis, n, 0);
  hop_k<<<gHop, 256, 0, stream>>>(Up, Z0, b1, h1, rowptr, colb, dis, n, 1);
  gemm_last_k<<<gGemm, 256, 0, stream>>>(h1, W2f, dis, GB, GBs3, n);

  // ----- Layer 2 Horner at D=16: f2=A g3'+g2; f1=A f2'+g1; out=A f1'+g0+b2
  spmm16_k<<<gS16, 256, 0, stream>>>(GBs3, GB + 32, 64, nullptr, nullptr, F0, rowptr, colb, dis, n);
  spmm16_k<<<gS16, 256, 0, stream>>>(F0,   GB + 16, 64, nullptr, nullptr, F1, rowptr, colb, dis, n);
  spmm16_k<<<gS16, 256, 0, stream>>>(F1,   GB + 0,  64, b2, out, nullptr, rowptr, colb, dis, n);
}